// Round 2
// baseline (1055.368 us; speedup 1.0000x reference)
//
#include <hip/hip_runtime.h>

typedef unsigned short u16;
typedef unsigned int   u32;
typedef short s16x8 __attribute__((ext_vector_type(8)));
typedef float f32x4 __attribute__((ext_vector_type(4)));

typedef const __attribute__((address_space(1))) void* gas_cvptr;
typedef __attribute__((address_space(3))) void* las_vptr;

#define T_TOK 8192
#define DDIM  1024
#define FDIM  4096

__device__ __forceinline__ float bf2f(u16 u){ u32 x=((u32)u)<<16; float f; __builtin_memcpy(&f,&x,4); return f; }
__device__ __forceinline__ u16 f2bf(float f){ u32 x; __builtin_memcpy(&x,&f,4); u32 r=(x+0x7fffu+((x>>16)&1u))>>16; return (u16)r; }

#define SBAR()  __builtin_amdgcn_s_barrier()

// ---------------- dtype detect: f32 inputs read as bf16 have huge-exponent halves ----------------
__global__ void k_detect(const u16* __restrict__ X, int* flagp, int* counts, float* scores){
  int lane=threadIdx.x;
  if(lane<8){ counts[lane]=0; scores[lane]=0.f; }
  float m=fmaxf(fabsf(bf2f(X[lane*2])),fabsf(bf2f(X[lane*2+1])));
  #pragma unroll
  for(int off=32;off>0;off>>=1) m=fmaxf(m,__shfl_xor(m,off,64));
  if(lane==0) *flagp = (m<=100.f)?0:1;  // NaN -> 1 (f32)
}

// ---------------- gating (full f32 math) + X -> bf16 cast + zero `out` (for gemm2 atomics) ----------------
__global__ __launch_bounds__(256) void k_gate(
    const void* __restrict__ Xv, const void* __restrict__ Wgv, const void* __restrict__ bgv,
    const int* __restrict__ flagp,
    int* counts, float* scores, int* eidx, float* wtok, u16* __restrict__ Xbf,
    float* __restrict__ out)
{
  int lane=threadIdx.x&63, wid=threadIdx.x>>6;
  int t=blockIdx.x*4+wid;
  int f32in=*flagp;
  float x[16];
  if(f32in){
    const float* xr=(const float*)Xv+(size_t)t*DDIM+lane*16;
    #pragma unroll
    for(int q=0;q<4;++q){
      f32x4 v=*(const f32x4*)(xr+q*4);
      x[q*4]=v[0]; x[q*4+1]=v[1]; x[q*4+2]=v[2]; x[q*4+3]=v[3];
    }
  }else{
    const u16* xr=(const u16*)Xv+(size_t)t*DDIM+lane*16;
    s16x8 a=*(const s16x8*)xr, b=*(const s16x8*)(xr+8);
    #pragma unroll
    for(int j=0;j<8;++j){ x[j]=bf2f((u16)a[j]); x[8+j]=bf2f((u16)b[j]); }
  }
  // write-through bf16 copy of X (GEMM1 A-operand source)
  s16x8 o0,o1;
  #pragma unroll
  for(int j=0;j<8;++j){ o0[j]=(short)f2bf(x[j]); o1[j]=(short)f2bf(x[8+j]); }
  u16* xw=Xbf+(size_t)t*DDIM+lane*16;
  *(s16x8*)xw=o0; *(s16x8*)(xw+8)=o1;

  // zero this token's output row (gemm2 accumulates atomically)
  #pragma unroll
  for(int q=0;q<4;++q)
    *(f32x4*)(out+(size_t)t*DDIM+q*256+lane*4)=(f32x4){0.f,0.f,0.f,0.f};

  float acc[8]={0,0,0,0,0,0,0,0};
  if(f32in){
    const float* wg=(const float*)Wgv;
    #pragma unroll
    for(int j=0;j<16;++j){
      const float* wr=wg+(size_t)(lane*16+j)*8;
      f32x4 w0=*(const f32x4*)wr, w1=*(const f32x4*)(wr+4);
      float xf=x[j];
      acc[0]+=xf*w0[0]; acc[1]+=xf*w0[1]; acc[2]+=xf*w0[2]; acc[3]+=xf*w0[3];
      acc[4]+=xf*w1[0]; acc[5]+=xf*w1[1]; acc[6]+=xf*w1[2]; acc[7]+=xf*w1[3];
    }
  }else{
    const u16* wg=(const u16*)Wgv;
    #pragma unroll
    for(int j=0;j<16;++j){
      s16x8 wv=*(const s16x8*)(wg+(size_t)(lane*16+j)*8);
      float xf=x[j];
      #pragma unroll
      for(int e=0;e<8;++e) acc[e]+=xf*bf2f((u16)wv[e]);
    }
  }
  #pragma unroll
  for(int e=0;e<8;++e){
    float v=acc[e];
    #pragma unroll
    for(int off=32;off>0;off>>=1) v+=__shfl_xor(v,off,64);
    acc[e]=v;
  }
  if(lane==0){
    float l[8],mx=-1e30f;
    #pragma unroll
    for(int e=0;e<8;++e){
      float bge = f32in ? ((const float*)bgv)[e] : bf2f(((const u16*)bgv)[e]);
      l[e]=acc[e]+bge; mx=fmaxf(mx,l[e]);
    }
    float p[8],s=0.f;
    #pragma unroll
    for(int e=0;e<8;++e){ p[e]=expf(l[e]-mx); s+=p[e]; }
    int arg=0; float best=p[0];
    #pragma unroll
    for(int e=1;e<8;++e) if(p[e]>best){best=p[e];arg=e;}  // first-max wins, matches jnp.argmax
    float w=best/s;
    eidx[t]=arg; wtok[t]=w;
    atomicAdd(&counts[arg],1);
    atomicAdd(&scores[arg],w);
  }
}

// ---------------- prefix + loss + tile descriptors (1 thread), 256-row tiles ----------------
__global__ void k_prefix(const int* counts, const float* scores,
                         int* offsets, int* cursor, int* desc, int* totalTiles, float* out_loss)
{
  if(threadIdx.x==0){
    int run=0, idx=0; float loss=0.f;
    for(int e=0;e<8;++e){
      offsets[e]=run; cursor[e]=run;
      int c=counts[e]; run+=c;
      float usage=scores[e]/((float)c+1e-8f);
      float d=usage-0.125f; loss+=d*d;
      int nt=(c+255)>>8;
      for(int m=0;m<nt;++m) desc[idx++]=(e<<16)|m;
    }
    *totalTiles=idx;
    out_loss[0]=loss;
  }
}

// ---------------- scatter tokens into expert buckets ----------------
__global__ __launch_bounds__(256) void k_scatter(const int* eidx, int* cursor, int* perm){
  int t=blockIdx.x*256+threadIdx.x;
  int e=eidx[t];
  int pos=atomicAdd(&cursor[e],1);
  perm[pos]=t;
}

// ---------------- 64x64 tile transpose+cast src[e][K][N] -> dst[e][N][K] bf16 ----------------
__global__ __launch_bounds__(256) void k_transpose(const void* __restrict__ srcv, u16* __restrict__ dst,
                                                   int K, int N, const int* __restrict__ flagp){
  int e=blockIdx.z;
  int f32in=*flagp;
  size_t ebase=(size_t)e*K*N;
  dst+=ebase;
  int k0=blockIdx.y*64, n0=blockIdx.x*64;
  __shared__ __align__(16) u16 tile[64*64];
  int tid=threadIdx.x;
  #pragma unroll
  for(int r=0;r<2;++r){
    int flat=r*256+tid;
    int k=flat>>3, ng=flat&7;
    s16x8 v;
    if(f32in){
      const float* s=(const float*)srcv+ebase+(size_t)(k0+k)*N+n0+ng*8;
      f32x4 a=*(const f32x4*)s, b=*(const f32x4*)(s+4);
      v[0]=(short)f2bf(a[0]); v[1]=(short)f2bf(a[1]); v[2]=(short)f2bf(a[2]); v[3]=(short)f2bf(a[3]);
      v[4]=(short)f2bf(b[0]); v[5]=(short)f2bf(b[1]); v[6]=(short)f2bf(b[2]); v[7]=(short)f2bf(b[3]);
    }else{
      v=*(const s16x8*)((const u16*)srcv+ebase+(size_t)(k0+k)*N+n0+ng*8);
    }
    int col=((ng^((k>>3)&7))<<3);
    *(s16x8*)&tile[k*64+col]=v;
  }
  __syncthreads();
  #pragma unroll
  for(int r=0;r<2;++r){
    int flat=r*256+tid;
    int n=flat>>3, kg=flat&7;
    int col=(((n>>3)^kg)<<3)|(n&7);
    s16x8 o;
    #pragma unroll
    for(int j=0;j<8;++j){
      int k=kg*8+j;
      o[j]=(short)tile[k*64+col];
    }
    *(s16x8*)(dst+(size_t)(n0+n)*K+k0+kg*8)=o;
  }
}

// ====================================================================================
// Relaxed ring-4 GEMM: BM=256, BK=32, 512 thr (8 waves 2Mx4N), 128 KiB LDS.
// ONE barrier + ONE counted vmcnt per K-tile; no intra-iteration barriers.
// Safety: reads touch slot t&3 only; staging writes slot (t+2)&3; wave skew <=1
// (one barrier/iter) so concurrent touches are always distinct mod 4.
// vmcnt(4) at iter end == tile t+1's 4 loads landed (t+2's 4 still in flight).
// Compiler free-schedules ds_read/MFMA interleave (fine lgkmcnt, per m97 evidence).
// ====================================================================================

// ---------------- GEMM1: H = Xg @ Wfc + bfc ; A = H1 * gelu(H2) ----------------
__global__ __launch_bounds__(512,2) void k_gemm1(
    const u16* __restrict__ Xbf, const u16* __restrict__ WfcT, const void* __restrict__ bfcv,
    u16* __restrict__ A, const int* __restrict__ perm, const int* __restrict__ counts,
    const int* __restrict__ offsets, const int* __restrict__ desc, const int* __restrict__ totalTiles,
    const int* __restrict__ flagp)
{
  if((int)blockIdx.y >= *totalTiles) return;
  int d=desc[blockIdx.y];
  int e=d>>16, mt=d&0xffff;
  int base=offsets[e], cnt=counts[e];
  int rowBase=base+mt*256, endRow=base+cnt;
  int n0=blockIdx.x*128;                       // 128 output A-cols per block

  __shared__ __align__(16) u16 lds_[4*16384];  // 128 KiB ring-4

  int tid=threadIdx.x, lane=tid&63, w=tid>>6;  // 8 waves
  int wy=w>>2, wx=w&3;

  // ---- staging pointers (inverse-swizzled global source) ----
  int cg=(lane&3)^((lane>>3)&3);               // swizzled 16B-chunk per lane
  const u16* pAg[2]; const u16* pBg[2];
  #pragma unroll
  for(int q=0;q<2;++q){
    int g=w*2+q;                               // 16 row-groups of 16 rows
    int rowg=g*16+(lane>>2);
    int s=rowBase+rowg; if(s>endRow-1)s=endRow-1;
    int tok=perm[s];
    pAg[q]=Xbf+(size_t)tok*DDIM+cg*8;
    int wxn=rowg>>6, cc=rowg&63;
    int gcol=n0+wxn*32+(cc&31)+((cc>=32)?FDIM:0);
    pBg[q]=WfcT+((size_t)e*2*FDIM+gcol)*DDIM+cg*8;
  }

  // ---- swizzled ds_read offsets (u16 units) ----
  int swz=((lane>>4)^((lane>>1)&3))*8;
  int aoff=(wy*128+(lane&15))*32+swz;          // + i*512
  int boff=8192+(wx*64+(lane&15))*32+swz;      // + j*512

  f32x4 acc[8][4];
  #pragma unroll
  for(int i=0;i<8;++i)
    #pragma unroll
    for(int j=0;j<4;++j) acc[i][j]=(f32x4){0.f,0.f,0.f,0.f};

  // ---- prologue: stage tiles 0,1 into slots 0,1 ----
  #pragma unroll
  for(int tt=0;tt<2;++tt){
    #pragma unroll
    for(int q=0;q<2;++q){
      __builtin_amdgcn_global_load_lds((gas_cvptr)pAg[q],(las_vptr)&lds_[tt*16384+(w*2+q)*512],16,0,0);
      pAg[q]+=32;
    }
    #pragma unroll
    for(int q=0;q<2;++q){
      __builtin_amdgcn_global_load_lds((gas_cvptr)pBg[q],(las_vptr)&lds_[tt*16384+8192+(w*2+q)*512],16,0,0);
      pBg[q]+=32;
    }
  }
  asm volatile("s_waitcnt vmcnt(4)" ::: "memory");   // tile 0 landed; tile 1 in flight
  SBAR();

  #pragma unroll 4
  for(int t=0;t<32;++t){
    u16* cb=&lds_[(t&3)*16384];
    int sslot=((t+2)&3)*16384;
    bool st=(t+2<32);
    // all 12 ds_reads for this K-tile (slot t&3 fully valid on entry)
    s16x8 bfr[4],af[4];
    #pragma unroll
    for(int j=0;j<4;++j) bfr[j]=*(const s16x8*)&cb[boff+j*512];
    #pragma unroll
    for(int i=0;i<4;++i) af[i]=*(const s16x8*)&cb[aoff+i*512];
    // stage A of tile t+2
    if(st){
      #pragma unroll
      for(int q=0;q<2;++q){
        __builtin_amdgcn_global_load_lds((gas_cvptr)pAg[q],(las_vptr)&lds_[sslot+(w*2+q)*512],16,0,0);
        pAg[q]+=32;
      }
    }
    #pragma unroll
    for(int i=0;i<4;++i)
      #pragma unroll
      for(int j=0;j<4;++j)
        acc[i][j]=__builtin_amdgcn_mfma_f32_16x16x32_bf16(af[i],bfr[j],acc[i][j],0,0,0);
    s16x8 af2[4];
    #pragma unroll
    for(int i=0;i<4;++i) af2[i]=*(const s16x8*)&cb[aoff+(4+i)*512];
    // stage B of tile t+2
    if(st){
      #pragma unroll
      for(int q=0;q<2;++q){
        __builtin_amdgcn_global_load_lds((gas_cvptr)pBg[q],(las_vptr)&lds_[sslot+8192+(w*2+q)*512],16,0,0);
        pBg[q]+=32;
      }
    }
    #pragma unroll
    for(int i=0;i<4;++i)
      #pragma unroll
      for(int j=0;j<4;++j)
        acc[4+i][j]=__builtin_amdgcn_mfma_f32_16x16x32_bf16(af2[i],bfr[j],acc[4+i][j],0,0,0);
    if(st) asm volatile("s_waitcnt vmcnt(4)" ::: "memory");  // tile t+1 landed; t+2 in flight
    else   asm volatile("s_waitcnt vmcnt(0)" ::: "memory");  // tail drain
    SBAR();
  }

  // ---- epilogue: acc[i][jn]=H1, acc[i][jn+2]=paired H2 ----
  int f32in=*flagp;
  #pragma unroll
  for(int jn=0;jn<2;++jn){
    int gA=n0+wx*32+jn*16+(lane&15);
    float b1,b2;
    if(f32in){
      b1=((const float*)bfcv)[(size_t)e*2*FDIM+gA];
      b2=((const float*)bfcv)[(size_t)e*2*FDIM+FDIM+gA];
    }else{
      b1=bf2f(((const u16*)bfcv)[(size_t)e*2*FDIM+gA]);
      b2=bf2f(((const u16*)bfcv)[(size_t)e*2*FDIM+FDIM+gA]);
    }
    #pragma unroll
    for(int i=0;i<8;++i){
      int rb=rowBase+wy*128+i*16+((lane>>4)*4);
      #pragma unroll
      for(int r=0;r<4;++r){
        int s=rb+r;
        if(s<endRow){
          float h1=acc[i][jn][r]+b1;
          float h2=acc[i][jn+2][r]+b2;
          float g=0.5f*h2*(1.0f+erff(h2*0.70710678118f)); // exact gelu
          A[(size_t)s*FDIM+gA]=f2bf(h1*g);
        }
      }
    }
  }
}

// ---------------- GEMM2 (split-K=4): out[tok] += (A @ Wout [+ bout]) * w[tok] via f32 atomics ----------------
__global__ __launch_bounds__(512,2) void k_gemm2(
    const u16* __restrict__ Aws, const u16* __restrict__ WoutT, const void* __restrict__ boutv,
    const float* __restrict__ wtok, const int* __restrict__ perm, const int* __restrict__ counts,
    const int* __restrict__ offsets, const int* __restrict__ desc, const int* __restrict__ totalTiles,
    const int* __restrict__ flagp, float* __restrict__ out)
{
  if((int)blockIdx.y >= *totalTiles) return;
  int d=desc[blockIdx.y];
  int e=d>>16, mt=d&0xffff;
  int base=offsets[e], cnt=counts[e];
  int rowBase=base+mt*256, endRow=base+cnt;
  int n0=blockIdx.x*256;                       // 256 output cols per block
  int kz=blockIdx.z*1024;                      // K-slice: [kz, kz+1024)

  __shared__ __align__(16) u16 lds_[4*16384];

  int tid=threadIdx.x, lane=tid&63, w=tid>>6;
  int wy=w>>2, wx=w&3;

  int cg=(lane&3)^((lane>>3)&3);
  const u16* pAg[2]; const u16* pBg[2];
  #pragma unroll
  for(int q=0;q<2;++q){
    int g=w*2+q;
    int rowg=g*16+(lane>>2);
    int s=rowBase+rowg; if(s>8319)s=8319;      // stay inside padded A workspace
    pAg[q]=Aws+(size_t)s*FDIM+kz+cg*8;
    pBg[q]=WoutT+((size_t)e*DDIM+n0+rowg)*FDIM+kz+cg*8;
  }

  int swz=((lane>>4)^((lane>>1)&3))*8;
  int aoff=(wy*128+(lane&15))*32+swz;
  int boff=8192+(wx*64+(lane&15))*32+swz;

  f32x4 acc[8][4];
  #pragma unroll
  for(int i=0;i<8;++i)
    #pragma unroll
    for(int j=0;j<4;++j) acc[i][j]=(f32x4){0.f,0.f,0.f,0.f};

  #pragma unroll
  for(int tt=0;tt<2;++tt){
    #pragma unroll
    for(int q=0;q<2;++q){
      __builtin_amdgcn_global_load_lds((gas_cvptr)pAg[q],(las_vptr)&lds_[tt*16384+(w*2+q)*512],16,0,0);
      pAg[q]+=32;
    }
    #pragma unroll
    for(int q=0;q<2;++q){
      __builtin_amdgcn_global_load_lds((gas_cvptr)pBg[q],(las_vptr)&lds_[tt*16384+8192+(w*2+q)*512],16,0,0);
      pBg[q]+=32;
    }
  }
  asm volatile("s_waitcnt vmcnt(4)" ::: "memory");
  SBAR();

  #pragma unroll 4
  for(int t=0;t<32;++t){
    u16* cb=&lds_[(t&3)*16384];
    int sslot=((t+2)&3)*16384;
    bool st=(t+2<32);
    s16x8 bfr[4],af[4];
    #pragma unroll
    for(int j=0;j<4;++j) bfr[j]=*(const s16x8*)&cb[boff+j*512];
    #pragma unroll
    for(int i=0;i<4;++i) af[i]=*(const s16x8*)&cb[aoff+i*512];
    if(st){
      #pragma unroll
      for(int q=0;q<2;++q){
        __builtin_amdgcn_global_load_lds((gas_cvptr)pAg[q],(las_vptr)&lds_[sslot+(w*2+q)*512],16,0,0);
        pAg[q]+=32;
      }
    }
    #pragma unroll
    for(int i=0;i<4;++i)
      #pragma unroll
      for(int j=0;j<4;++j)
        acc[i][j]=__builtin_amdgcn_mfma_f32_16x16x32_bf16(af[i],bfr[j],acc[i][j],0,0,0);
    s16x8 af2[4];
    #pragma unroll
    for(int i=0;i<4;++i) af2[i]=*(const s16x8*)&cb[aoff+(4+i)*512];
    if(st){
      #pragma unroll
      for(int q=0;q<2;++q){
        __builtin_amdgcn_global_load_lds((gas_cvptr)pBg[q],(las_vptr)&lds_[sslot+8192+(w*2+q)*512],16,0,0);
        pBg[q]+=32;
      }
    }
    #pragma unroll
    for(int i=0;i<4;++i)
      #pragma unroll
      for(int j=0;j<4;++j)
        acc[4+i][j]=__builtin_amdgcn_mfma_f32_16x16x32_bf16(af2[i],bfr[j],acc[4+i][j],0,0,0);
    if(st) asm volatile("s_waitcnt vmcnt(4)" ::: "memory");
    else   asm volatile("s_waitcnt vmcnt(0)" ::: "memory");
    SBAR();
  }

  int f32in=*flagp;
  int z0=(blockIdx.z==0);
  #pragma unroll
  for(int i=0;i<8;++i){
    int rb=rowBase+wy*128+i*16+((lane>>4)*4);
    #pragma unroll
    for(int r=0;r<4;++r){
      int s=rb+r;
      if(s<endRow){
        int tok=perm[s];
        float wv=wtok[tok];
        #pragma unroll
        for(int j=0;j<4;++j){
          int col=n0+wx*64+j*16+(lane&15);
          float v=acc[i][j][r];
          if(z0){
            float be = f32in ? ((const float*)boutv)[(size_t)e*DDIM+col]
                             : bf2f(((const u16*)boutv)[(size_t)e*DDIM+col]);
            v+=be;
          }
          atomicAdd(&out[(size_t)tok*DDIM+col],v*wv);
        }
      }
    }
  }
}

// ---------------- launch ----------------
// ws layout (bytes), total ~274 MiB:
//   0 counts[8] | 32 cursor[8] | 64 scores[8] | 96 offsets[8] | 128 totalTiles
//   160 flag | 192 desc[96] | 576 eidx[8192] | 33344 wtok[8192] | 66112 perm[8192]
//   1<<20          Xbf  bf16[8192*1024]         16,777,216 B
//   17,825,792     A    bf16[(8192+128)*4096]   68,157,440 B
//   85,983,232     WfcT bf16[8*8192*1024]      134,217,728 B
//   220,200,960    WoutT bf16[8*1024*4096]      67,108,864 B
extern "C" void kernel_launch(void* const* d_in, const int* in_sizes, int n_in,
                              void* d_out, int out_size, void* d_ws, size_t ws_size,
                              hipStream_t stream) {
  const void* X    =d_in[0];
  const void* Wg   =d_in[1];
  const void* bg   =d_in[2];
  const void* Wfc  =d_in[3];
  const void* bfc  =d_in[4];
  const void* Wout =d_in[5];
  const void* bout =d_in[6];
  float* out=(float*)d_out;

  char* ws=(char*)d_ws;
  int*   counts =(int*)  (ws+0);
  int*   cursor =(int*)  (ws+32);
  float* scores =(float*)(ws+64);
  int*   offsets=(int*)  (ws+96);
  int*   total  =(int*)  (ws+128);
  int*   flag   =(int*)  (ws+160);
  int*   desc   =(int*)  (ws+192);
  int*   eidx   =(int*)  (ws+576);
  float* wtok   =(float*)(ws+33344);
  int*   perm   =(int*)  (ws+66112);
  u16*   Xbf    =(u16*)  (ws+(1ull<<20));
  u16*   A      =(u16*)  (ws+17825792ull);
  u16*   WfcT   =(u16*)  (ws+85983232ull);
  u16*   WoutT  =(u16*)  (ws+220200960ull);

  k_detect<<<1,64,0,stream>>>((const u16*)X,flag,counts,scores);
  k_gate<<<2048,256,0,stream>>>(X,Wg,bg,flag,counts,scores,eidx,wtok,Xbf,out);
  k_prefix<<<1,64,0,stream>>>(counts,scores,offsets,cursor,desc,total,out+(size_t)T_TOK*DDIM);
  k_scatter<<<32,256,0,stream>>>(eidx,cursor,perm);
  k_transpose<<<dim3(128,16,8),256,0,stream>>>(Wfc,WfcT,DDIM,2*FDIM,flag);
  k_transpose<<<dim3(16,64,8),256,0,stream>>>(Wout,WoutT,FDIM,DDIM,flag);
  k_gemm1<<<dim3(32,40),512,0,stream>>>(Xbf,WfcT,bfc,A,perm,counts,offsets,desc,total,flag);
  k_gemm2<<<dim3(4,40,4),512,0,stream>>>(A,WoutT,bout,wtok,perm,counts,offsets,desc,total,flag,out);
}

// Round 4
// 978.271 us; speedup vs baseline: 1.0788x; 1.0788x over previous
//
#include <hip/hip_runtime.h>

typedef unsigned short u16;
typedef unsigned int   u32;
typedef short s16x8 __attribute__((ext_vector_type(8)));
typedef float f32x4 __attribute__((ext_vector_type(4)));
typedef float f32x16 __attribute__((ext_vector_type(16)));

typedef const __attribute__((address_space(1))) void* gas_cvptr;
typedef __attribute__((address_space(3))) void* las_vptr;

#define T_TOK 8192
#define DDIM  1024
#define FDIM  4096

__device__ __forceinline__ float bf2f(u16 u){ u32 x=((u32)u)<<16; float f; __builtin_memcpy(&f,&x,4); return f; }
__device__ __forceinline__ u16 f2bf(float f){ u32 x; __builtin_memcpy(&x,&f,4); u32 r=(x+0x7fffu+((x>>16)&1u))>>16; return (u16)r; }

#define SBAR()  __builtin_amdgcn_s_barrier()

// fast exact-to-1.5e-7 gelu via Abramowitz-Stegun 7.1.26 erf
__device__ __forceinline__ float gelu_fast(float h){
  float x = h*0.70710678118f;
  float ax = fabsf(x);
  float t = __builtin_amdgcn_rcpf(1.0f + 0.3275911f*ax);
  float y = t*(0.254829592f + t*(-0.284496736f + t*(1.421413741f + t*(-1.453152027f + t*1.061405429f))));
  float ex = __expf(-x*x);
  float er = 1.0f - y*ex;
  er = (x<0.0f)? -er : er;
  return 0.5f*h*(1.0f+er);
}

// ---------------- dtype detect: f32 inputs read as bf16 have huge-exponent halves ----------------
__global__ void k_detect(const u16* __restrict__ X, int* flagp, int* counts, float* scores){
  int lane=threadIdx.x;
  if(lane<8){ counts[lane]=0; scores[lane]=0.f; }
  float m=fmaxf(fabsf(bf2f(X[lane*2])),fabsf(bf2f(X[lane*2+1])));
  #pragma unroll
  for(int off=32;off>0;off>>=1) m=fmaxf(m,__shfl_xor(m,off,64));
  if(lane==0) *flagp = (m<=100.f)?0:1;  // NaN -> 1 (f32)
}

// ---------------- gating (full f32 math) + X -> bf16 workspace cast ----------------
__global__ __launch_bounds__(256) void k_gate(
    const void* __restrict__ Xv, const void* __restrict__ Wgv, const void* __restrict__ bgv,
    const int* __restrict__ flagp,
    int* counts, float* scores, int* eidx, float* wtok, u16* __restrict__ Xbf)
{
  int lane=threadIdx.x&63, wid=threadIdx.x>>6;
  int t=blockIdx.x*4+wid;
  int f32in=*flagp;
  float x[16];
  if(f32in){
    const float* xr=(const float*)Xv+(size_t)t*DDIM+lane*16;
    #pragma unroll
    for(int q=0;q<4;++q){
      f32x4 v=*(const f32x4*)(xr+q*4);
      x[q*4]=v[0]; x[q*4+1]=v[1]; x[q*4+2]=v[2]; x[q*4+3]=v[3];
    }
  }else{
    const u16* xr=(const u16*)Xv+(size_t)t*DDIM+lane*16;
    s16x8 a=*(const s16x8*)xr, b=*(const s16x8*)(xr+8);
    #pragma unroll
    for(int j=0;j<8;++j){ x[j]=bf2f((u16)a[j]); x[8+j]=bf2f((u16)b[j]); }
  }
  // write-through bf16 copy of X (GEMM1 A-operand source)
  s16x8 o0,o1;
  #pragma unroll
  for(int j=0;j<8;++j){ o0[j]=(short)f2bf(x[j]); o1[j]=(short)f2bf(x[8+j]); }
  u16* xw=Xbf+(size_t)t*DDIM+lane*16;
  *(s16x8*)xw=o0; *(s16x8*)(xw+8)=o1;

  float acc[8]={0,0,0,0,0,0,0,0};
  if(f32in){
    const float* wg=(const float*)Wgv;
    #pragma unroll
    for(int j=0;j<16;++j){
      const float* wr=wg+(size_t)(lane*16+j)*8;
      f32x4 w0=*(const f32x4*)wr, w1=*(const f32x4*)(wr+4);
      float xf=x[j];
      acc[0]+=xf*w0[0]; acc[1]+=xf*w0[1]; acc[2]+=xf*w0[2]; acc[3]+=xf*w0[3];
      acc[4]+=xf*w1[0]; acc[5]+=xf*w1[1]; acc[6]+=xf*w1[2]; acc[7]+=xf*w1[3];
    }
  }else{
    const u16* wg=(const u16*)Wgv;
    #pragma unroll
    for(int j=0;j<16;++j){
      s16x8 wv=*(const s16x8*)(wg+(size_t)(lane*16+j)*8);
      float xf=x[j];
      #pragma unroll
      for(int e=0;e<8;++e) acc[e]+=xf*bf2f((u16)wv[e]);
    }
  }
  #pragma unroll
  for(int e=0;e<8;++e){
    float v=acc[e];
    #pragma unroll
    for(int off=32;off>0;off>>=1) v+=__shfl_xor(v,off,64);
    acc[e]=v;
  }
  if(lane==0){
    float l[8],mx=-1e30f;
    #pragma unroll
    for(int e=0;e<8;++e){
      float bge = f32in ? ((const float*)bgv)[e] : bf2f(((const u16*)bgv)[e]);
      l[e]=acc[e]+bge; mx=fmaxf(mx,l[e]);
    }
    float p[8],s=0.f;
    #pragma unroll
    for(int e=0;e<8;++e){ p[e]=expf(l[e]-mx); s+=p[e]; }
    int arg=0; float best=p[0];
    #pragma unroll
    for(int e=1;e<8;++e) if(p[e]>best){best=p[e];arg=e;}  // first-max wins, matches jnp.argmax
    float w=best/s;
    eidx[t]=arg; wtok[t]=w;
    atomicAdd(&counts[arg],1);
    atomicAdd(&scores[arg],w);
  }
}

// ---------------- prefix + loss + tile descriptors (1 thread), 256-row tiles ----------------
__global__ void k_prefix(const int* counts, const float* scores,
                         int* offsets, int* cursor, int* desc, int* totalTiles, float* out_loss)
{
  if(threadIdx.x==0){
    int run=0, idx=0; float loss=0.f;
    for(int e=0;e<8;++e){
      offsets[e]=run; cursor[e]=run;
      int c=counts[e]; run+=c;
      float usage=scores[e]/((float)c+1e-8f);
      float d=usage-0.125f; loss+=d*d;
      int nt=(c+255)>>8;
      for(int m=0;m<nt;++m) desc[idx++]=(e<<16)|m;
    }
    *totalTiles=idx;
    out_loss[0]=loss;
  }
}

// ---------------- scatter tokens into expert buckets ----------------
__global__ __launch_bounds__(256) void k_scatter(const int* eidx, int* cursor, int* perm){
  int t=blockIdx.x*256+threadIdx.x;
  int e=eidx[t];
  int pos=atomicAdd(&cursor[e],1);
  perm[pos]=t;
}

// ---------------- 128x128 tile transpose+cast src[e][K][N] -> dst[e][N][K] bf16 ----------------
// Reads 512B-contiguous per src row (f32) / 256B (bf16); writes 256B-contiguous per dst row.
// LDS chunk swizzle c' = c ^ kg keeps both phases ~conflict-free.
__global__ __launch_bounds__(256) void k_transpose(const void* __restrict__ srcv, u16* __restrict__ dst,
                                                   int K, int N, const int* __restrict__ flagp){
  int e=blockIdx.z;
  int f32in=*flagp;
  size_t ebase=(size_t)e*K*N;
  dst+=ebase;
  int n0=blockIdx.x*128, k0=blockIdx.y*128;
  __shared__ __align__(16) u16 tile[128*128];   // 32 KiB
  int tid=threadIdx.x;
  #pragma unroll
  for(int r=0;r<8;++r){
    int flat=r*256+tid;
    int k=flat>>4, ng=flat&15;
    s16x8 v;
    if(f32in){
      const float* s=(const float*)srcv+ebase+(size_t)(k0+k)*N+n0+ng*8;
      f32x4 a=*(const f32x4*)s, b=*(const f32x4*)(s+4);
      v[0]=(short)f2bf(a[0]); v[1]=(short)f2bf(a[1]); v[2]=(short)f2bf(a[2]); v[3]=(short)f2bf(a[3]);
      v[4]=(short)f2bf(b[0]); v[5]=(short)f2bf(b[1]); v[6]=(short)f2bf(b[2]); v[7]=(short)f2bf(b[3]);
    }else{
      v=*(const s16x8*)((const u16*)srcv+ebase+(size_t)(k0+k)*N+n0+ng*8);
    }
    int c=(ng^((k>>3)&15))<<3;
    *(s16x8*)&tile[k*128+c]=v;
  }
  __syncthreads();
  #pragma unroll
  for(int r=0;r<8;++r){
    int flat=r*256+tid;
    int n=flat>>4, kg=flat&15;
    int cp=((n>>3)^kg)<<3;   // (kg*8+j)>>3 == kg for j<8
    s16x8 o;
    #pragma unroll
    for(int j=0;j<8;++j){
      o[j]=(short)tile[(kg*8+j)*128+cp+(n&7)];
    }
    *(s16x8*)(dst+(size_t)(n0+n)*K+k0+kg*8)=o;
  }
}

// ====================================================================================
// Relaxed ring-4 GEMM, 32x32x16 MFMA: BM=256, BK=32, 512 thr (8 waves 2Mx4N), 128 KiB.
// One barrier + one counted vmcnt per K-tile (R2-verified correct).
// Wave tile 128x64 as 4x2 grid of 32x32 fragments, K=32 as 2 halves of 16.
// A-frag: row=lane&31, k=(lane>>5)*8+j.  C/D: col=lane&31, row=(reg&3)+8*(reg>>2)+4*(lane>>5)
// (m74/m101-verified). LDS swizzle: chunk' = chunk ^ ((row>>1)&3) (16B chunks, 4/row).
// ====================================================================================

// ---------------- GEMM1: H = Xg @ Wfc + bfc ; A = H1 * gelu(H2) ----------------
__global__ __launch_bounds__(512,2) void k_gemm1(
    const u16* __restrict__ Xbf, const u16* __restrict__ WfcT, const void* __restrict__ bfcv,
    u16* __restrict__ A, const int* __restrict__ perm, const int* __restrict__ counts,
    const int* __restrict__ offsets, const int* __restrict__ desc, const int* __restrict__ totalTiles,
    const int* __restrict__ flagp)
{
  if((int)blockIdx.y >= *totalTiles) return;
  int d=desc[blockIdx.y];
  int e=d>>16, mt=d&0xffff;
  int base=offsets[e], cnt=counts[e];
  int rowBase=base+mt*256, endRow=base+cnt;
  int n0=blockIdx.x*128;                       // 128 output A-cols per block

  __shared__ __align__(16) u16 lds_[4*16384];  // 128 KiB ring-4

  int tid=threadIdx.x, lane=tid&63, w=tid>>6;  // 8 waves
  int wy=w>>2, wx=w&3;

  // ---- staging pointers (inverse-swizzled global source) ----
  int cg=(lane&3)^((lane>>3)&3);               // swizzled 16B-chunk per lane
  const u16* pAg[2]; const u16* pBg[2];
  #pragma unroll
  for(int q=0;q<2;++q){
    int g=w*2+q;                               // 16 row-groups of 16 rows
    int rowg=g*16+(lane>>2);
    int s=rowBase+rowg; if(s>endRow-1)s=endRow-1;
    int tok=perm[s];
    pAg[q]=Xbf+(size_t)tok*DDIM+cg*8;
    int wxn=rowg>>6, cc=rowg&63;
    int gcol=n0+wxn*32+(cc&31)+((cc>=32)?FDIM:0);
    pBg[q]=WfcT+((size_t)e*2*FDIM+gcol)*DDIM+cg*8;
  }

  // ---- swizzled ds_read offsets (u16 units) ----
  int r5=lane&31, cb=lane>>5, sx=(r5>>1)&3;
  int c0=(cb^sx)*8, c1=((2+cb)^sx)*8;          // chunk offsets for k-half 0 / 1
  int aBase=(wy*128+r5)*32;                    // + i*1024 + c0/c1
  int bBase=8192+(wx*64+r5)*32;                // + jb*1024 + c0/c1

  f32x16 acc[4][2];
  #pragma unroll
  for(int i=0;i<4;++i)
    #pragma unroll
    for(int j=0;j<2;++j) acc[i][j]=(f32x16)(0.0f);

  // ---- prologue: stage tiles 0,1 into slots 0,1 ----
  #pragma unroll
  for(int tt=0;tt<2;++tt){
    #pragma unroll
    for(int q=0;q<2;++q){
      __builtin_amdgcn_global_load_lds((gas_cvptr)pAg[q],(las_vptr)&lds_[tt*16384+(w*2+q)*512],16,0,0);
      pAg[q]+=32;
    }
    #pragma unroll
    for(int q=0;q<2;++q){
      __builtin_amdgcn_global_load_lds((gas_cvptr)pBg[q],(las_vptr)&lds_[tt*16384+8192+(w*2+q)*512],16,0,0);
      pBg[q]+=32;
    }
  }
  asm volatile("s_waitcnt vmcnt(4)" ::: "memory");   // tile 0 landed; tile 1 in flight
  SBAR();

  #pragma unroll 4
  for(int t=0;t<32;++t){
    u16* cb_=&lds_[(t&3)*16384];
    int sslot=((t+2)&3)*16384;
    bool st=(t+2<32);
    // k-half 0
    s16x8 af[4],bfr[2];
    #pragma unroll
    for(int j=0;j<2;++j) bfr[j]=*(const s16x8*)&cb_[bBase+j*1024+c0];
    #pragma unroll
    for(int i=0;i<4;++i) af[i]=*(const s16x8*)&cb_[aBase+i*1024+c0];
    if(st){
      #pragma unroll
      for(int q=0;q<2;++q){
        __builtin_amdgcn_global_load_lds((gas_cvptr)pAg[q],(las_vptr)&lds_[sslot+(w*2+q)*512],16,0,0);
        pAg[q]+=32;
      }
    }
    #pragma unroll
    for(int i=0;i<4;++i)
      #pragma unroll
      for(int j=0;j<2;++j)
        acc[i][j]=__builtin_amdgcn_mfma_f32_32x32x16_bf16(af[i],bfr[j],acc[i][j],0,0,0);
    // k-half 1
    s16x8 af2[4],bfr2[2];
    #pragma unroll
    for(int j=0;j<2;++j) bfr2[j]=*(const s16x8*)&cb_[bBase+j*1024+c1];
    #pragma unroll
    for(int i=0;i<4;++i) af2[i]=*(const s16x8*)&cb_[aBase+i*1024+c1];
    if(st){
      #pragma unroll
      for(int q=0;q<2;++q){
        __builtin_amdgcn_global_load_lds((gas_cvptr)pBg[q],(las_vptr)&lds_[sslot+8192+(w*2+q)*512],16,0,0);
        pBg[q]+=32;
      }
    }
    #pragma unroll
    for(int i=0;i<4;++i)
      #pragma unroll
      for(int j=0;j<2;++j)
        acc[i][j]=__builtin_amdgcn_mfma_f32_32x32x16_bf16(af2[i],bfr2[j],acc[i][j],0,0,0);
    if(st) asm volatile("s_waitcnt vmcnt(4)" ::: "memory");  // tile t+1 landed; t+2 in flight
    else   asm volatile("s_waitcnt vmcnt(0)" ::: "memory");  // tail drain
    SBAR();
  }

  // ---- epilogue: acc[i][0]=H1, acc[i][1]=paired H2 (register-local) ----
  int f32in=*flagp;
  int c5=lane&31, hi=lane>>5;
  int gA=n0+wx*32+c5;
  float b1,b2;
  if(f32in){
    b1=((const float*)bfcv)[(size_t)e*2*FDIM+gA];
    b2=((const float*)bfcv)[(size_t)e*2*FDIM+FDIM+gA];
  }else{
    b1=bf2f(((const u16*)bfcv)[(size_t)e*2*FDIM+gA]);
    b2=bf2f(((const u16*)bfcv)[(size_t)e*2*FDIM+FDIM+gA]);
  }
  #pragma unroll
  for(int i=0;i<4;++i){
    #pragma unroll
    for(int reg=0;reg<16;++reg){
      int row=(reg&3)+8*(reg>>2)+4*hi;
      int s=rowBase+wy*128+i*32+row;
      if(s<endRow){
        float h1=acc[i][0][reg]+b1;
        float h2=acc[i][1][reg]+b2;
        A[(size_t)s*FDIM+gA]=f2bf(h1*gelu_fast(h2));
      }
    }
  }
}

// ---------------- GEMM2: out[tok] = (A @ Wout + bout) * w[tok]  (f32 output) ----------------
__global__ __launch_bounds__(512,2) void k_gemm2(
    const u16* __restrict__ Aws, const u16* __restrict__ WoutT, const void* __restrict__ boutv,
    const float* __restrict__ wtok, const int* __restrict__ perm, const int* __restrict__ counts,
    const int* __restrict__ offsets, const int* __restrict__ desc, const int* __restrict__ totalTiles,
    const int* __restrict__ flagp, float* __restrict__ out)
{
  if((int)blockIdx.y >= *totalTiles) return;
  int d=desc[blockIdx.y];
  int e=d>>16, mt=d&0xffff;
  int base=offsets[e], cnt=counts[e];
  int rowBase=base+mt*256, endRow=base+cnt;
  int n0=blockIdx.x*256;                       // 256 output cols per block

  __shared__ __align__(16) u16 lds_[4*16384];

  int tid=threadIdx.x, lane=tid&63, w=tid>>6;
  int wy=w>>2, wx=w&3;

  int cg=(lane&3)^((lane>>3)&3);
  const u16* pAg[2]; const u16* pBg[2];
  #pragma unroll
  for(int q=0;q<2;++q){
    int g=w*2+q;
    int rowg=g*16+(lane>>2);
    int s=rowBase+rowg; if(s>8319)s=8319;      // stay inside padded A workspace
    pAg[q]=Aws+(size_t)s*FDIM+cg*8;
    pBg[q]=WoutT+((size_t)e*DDIM+n0+rowg)*FDIM+cg*8;
  }

  int r5=lane&31, cb=lane>>5, sx=(r5>>1)&3;
  int c0=(cb^sx)*8, c1=((2+cb)^sx)*8;
  int aBase=(wy*128+r5)*32;
  int bBase=8192+(wx*64+r5)*32;

  f32x16 acc[4][2];
  #pragma unroll
  for(int i=0;i<4;++i)
    #pragma unroll
    for(int j=0;j<2;++j) acc[i][j]=(f32x16)(0.0f);

  #pragma unroll
  for(int tt=0;tt<2;++tt){
    #pragma unroll
    for(int q=0;q<2;++q){
      __builtin_amdgcn_global_load_lds((gas_cvptr)pAg[q],(las_vptr)&lds_[tt*16384+(w*2+q)*512],16,0,0);
      pAg[q]+=32;
    }
    #pragma unroll
    for(int q=0;q<2;++q){
      __builtin_amdgcn_global_load_lds((gas_cvptr)pBg[q],(las_vptr)&lds_[tt*16384+8192+(w*2+q)*512],16,0,0);
      pBg[q]+=32;
    }
  }
  asm volatile("s_waitcnt vmcnt(4)" ::: "memory");
  SBAR();

  #pragma unroll 4
  for(int t=0;t<128;++t){
    u16* cb_=&lds_[(t&3)*16384];
    int sslot=((t+2)&3)*16384;
    bool st=(t+2<128);
    s16x8 af[4],bfr[2];
    #pragma unroll
    for(int j=0;j<2;++j) bfr[j]=*(const s16x8*)&cb_[bBase+j*1024+c0];
    #pragma unroll
    for(int i=0;i<4;++i) af[i]=*(const s16x8*)&cb_[aBase+i*1024+c0];
    if(st){
      #pragma unroll
      for(int q=0;q<2;++q){
        __builtin_amdgcn_global_load_lds((gas_cvptr)pAg[q],(las_vptr)&lds_[sslot+(w*2+q)*512],16,0,0);
        pAg[q]+=32;
      }
    }
    #pragma unroll
    for(int i=0;i<4;++i)
      #pragma unroll
      for(int j=0;j<2;++j)
        acc[i][j]=__builtin_amdgcn_mfma_f32_32x32x16_bf16(af[i],bfr[j],acc[i][j],0,0,0);
    s16x8 af2[4],bfr2[2];
    #pragma unroll
    for(int j=0;j<2;++j) bfr2[j]=*(const s16x8*)&cb_[bBase+j*1024+c1];
    #pragma unroll
    for(int i=0;i<4;++i) af2[i]=*(const s16x8*)&cb_[aBase+i*1024+c1];
    if(st){
      #pragma unroll
      for(int q=0;q<2;++q){
        __builtin_amdgcn_global_load_lds((gas_cvptr)pBg[q],(las_vptr)&lds_[sslot+8192+(w*2+q)*512],16,0,0);
        pBg[q]+=32;
      }
    }
    #pragma unroll
    for(int i=0;i<4;++i)
      #pragma unroll
      for(int j=0;j<2;++j)
        acc[i][j]=__builtin_amdgcn_mfma_f32_32x32x16_bf16(af2[i],bfr2[j],acc[i][j],0,0,0);
    if(st) asm volatile("s_waitcnt vmcnt(4)" ::: "memory");
    else   asm volatile("s_waitcnt vmcnt(0)" ::: "memory");
    SBAR();
  }

  int f32in=*flagp;
  int c5=lane&31, hi=lane>>5;
  int col0=n0+wx*64+c5, col1=col0+32;
  float be0,be1;
  if(f32in){
    be0=((const float*)boutv)[(size_t)e*DDIM+col0];
    be1=((const float*)boutv)[(size_t)e*DDIM+col1];
  }else{
    be0=bf2f(((const u16*)boutv)[(size_t)e*DDIM+col0]);
    be1=bf2f(((const u16*)boutv)[(size_t)e*DDIM+col1]);
  }
  #pragma unroll
  for(int i=0;i<4;++i){
    #pragma unroll
    for(int reg=0;reg<16;++reg){
      int row=(reg&3)+8*(reg>>2)+4*hi;
      int s=rowBase+wy*128+i*32+row;
      if(s<endRow){
        int tok=perm[s];
        float wv=wtok[tok];
        out[(size_t)tok*DDIM+col0]=(acc[i][0][reg]+be0)*wv;
        out[(size_t)tok*DDIM+col1]=(acc[i][1][reg]+be1)*wv;
      }
    }
  }
}

// ---------------- launch ----------------
// ws layout (bytes), total ~274 MiB:
//   0 counts[8] | 32 cursor[8] | 64 scores[8] | 96 offsets[8] | 128 totalTiles
//   160 flag | 192 desc[96] | 576 eidx[8192] | 33344 wtok[8192] | 66112 perm[8192]
//   1<<20          Xbf  bf16[8192*1024]         16,777,216 B
//   17,825,792     A    bf16[(8192+128)*4096]   68,157,440 B
//   85,983,232     WfcT bf16[8*8192*1024]      134,217,728 B
//   220,200,960    WoutT bf16[8*1024*4096]      67,108,864 B
extern "C" void kernel_launch(void* const* d_in, const int* in_sizes, int n_in,
                              void* d_out, int out_size, void* d_ws, size_t ws_size,
                              hipStream_t stream) {
  const void* X    =d_in[0];
  const void* Wg   =d_in[1];
  const void* bg   =d_in[2];
  const void* Wfc  =d_in[3];
  const void* bfc  =d_in[4];
  const void* Wout =d_in[5];
  const void* bout =d_in[6];
  float* out=(float*)d_out;

  char* ws=(char*)d_ws;
  int*   counts =(int*)  (ws+0);
  int*   cursor =(int*)  (ws+32);
  float* scores =(float*)(ws+64);
  int*   offsets=(int*)  (ws+96);
  int*   total  =(int*)  (ws+128);
  int*   flag   =(int*)  (ws+160);
  int*   desc   =(int*)  (ws+192);
  int*   eidx   =(int*)  (ws+576);
  float* wtok   =(float*)(ws+33344);
  int*   perm   =(int*)  (ws+66112);
  u16*   Xbf    =(u16*)  (ws+(1ull<<20));
  u16*   A      =(u16*)  (ws+17825792ull);
  u16*   WfcT   =(u16*)  (ws+85983232ull);
  u16*   WoutT  =(u16*)  (ws+220200960ull);

  k_detect<<<1,64,0,stream>>>((const u16*)X,flag,counts,scores);
  k_gate<<<2048,256,0,stream>>>(X,Wg,bg,flag,counts,scores,eidx,wtok,Xbf);
  k_prefix<<<1,64,0,stream>>>(counts,scores,offsets,cursor,desc,total,out+(size_t)T_TOK*DDIM);
  k_scatter<<<32,256,0,stream>>>(eidx,cursor,perm);
  k_transpose<<<dim3(64,8,8),256,0,stream>>>(Wfc,WfcT,DDIM,2*FDIM,flag);
  k_transpose<<<dim3(8,32,8),256,0,stream>>>(Wout,WoutT,FDIM,DDIM,flag);
  k_gemm1<<<dim3(32,40),512,0,stream>>>(Xbf,WfcT,bfc,A,perm,counts,offsets,desc,total,flag);
  k_gemm2<<<dim3(4,40),512,0,stream>>>(A,WoutT,bout,wtok,perm,counts,offsets,desc,total,flag,out);
}